// Round 11
// baseline (92.402 us; speedup 1.0000x reference)
//
#include <hip/hip_runtime.h>
#include <math.h>

#define DIM  4096
#define BLK  1024           // 16 waves; TWO elements per block (tid bit 9)
#define NPAR 144

typedef float v2f __attribute__((ext_vector_type(2)));

// ---------------------------------------------------------------------------
// Per element (t9 = tid & 511): 12 canonical bits = 3 reg + 3 wave (t9 6..8)
// + 6 lane (t9 0..5). R6-R9-validated 12-epoch schedule and GF(2) slot maps.
// Wave-pinned runs -> wave-local restages (no barrier, no waitcnt: LDS is
// in-order per wave). Shared reg bit -> full b128 stash AND unstash.
// Angles in lane-distributed VGPRs via v_readlane.
// R11: two independent elements per block (64 blocks x 1024 thr) so each
// SIMD hosts 2 waves of EACH element -> independent chains fill the restage
// drain stalls. Single cross buffer per element (barrier-stash-barrier-
// unstash) to fit 128 KB LDS.
// ---------------------------------------------------------------------------
struct Ph { int reg[3]; int wav[3]; };
struct TMap { unsigned pk[9]; unsigned short so[8]; unsigned short rn[8]; };

constexpr int REGS[12][3] = {
  {11,0,1},{1,2,3},{3,4,5},{5,6,7},{7,8,9},{9,10,11},
  {11,0,1},{9,10,11},{7,8,9},{5,6,7},{3,4,5},{1,2,3}};

constexpr Ph phaseAt(int i) {         // i = 0..37; 0/37 = global pseudo-phase
  Ph p = {};
  if (i == 0 || i == 37) {
    p.reg[0]=0; p.reg[1]=1; p.reg[2]=2;
    p.wav[0]=9; p.wav[1]=10; p.wav[2]=11;
    return p;
  }
  int e = (i - 1) % 12;
  for (int j = 0; j < 3; ++j) p.reg[j] = REGS[e][j];
  bool A = (e <= 2) || (e >= 10);     // pin {6,7,8} else {2,3,4}
  p.wav[0] = A ? 6 : 2; p.wav[1] = A ? 7 : 3; p.wav[2] = A ? 8 : 4;
  return p;
}
constexpr bool inArr(const int* a, int n, int b) {
  for (int i = 0; i < n; ++i) if (a[i] == b) return true;
  return false;
}
constexpr int idxOf3(const int* a, int v) {
  for (int j = 0; j < 3; ++j) if (a[j] == v) return j;
  return -1;
}
constexpr bool isLoc(int t) {
  if (t == 0 || t == 36) return false;
  Ph a = phaseAt(t), b = phaseAt(t + 1);
  return a.wav[0]==b.wav[0] && a.wav[1]==b.wav[1] && a.wav[2]==b.wav[2];
}
constexpr int sharedBit(Ph o, Ph n) {
  for (int j = 0; j < 3; ++j) if (inArr(n.reg, 3, o.reg[j])) return o.reg[j];
  return -1;
}

struct BuildOut { TMap m; int js, jn; bool ok; };

// GF(2)-linear canonical->slot map (R7-validated). Row 0 = shared reg bit
// (b128 pairing both sides). Rows 1..3 = lane bits of both phases (bank-
// conflict-free b128). Local: wave bits -> rows 9..11 (private 4 KB/wave).
constexpr BuildOut buildT(Ph o, Ph n, bool local) {
  BuildOut R = {};
  R.ok = true;
  int s = sharedBit(o, n);
  if (s < 0) { R.ok = false; return R; }
  R.js = idxOf3(o.reg, s);
  R.jn = idxOf3(n.reg, s);
  if (R.js < 0 || R.jn < 0) { R.ok = false; return R; }
  bool lo[12] = {}, ln[12] = {};
  for (int b = 0; b < 12; ++b) {
    lo[b] = !inArr(o.reg,3,b) && !inArr(o.wav,3,b);
    ln[b] = !inArr(n.reg,3,b) && !inArr(n.wav,3,b);
  }
  int col[12] = {};
  bool uo[12] = {}, un[12] = {}, consumed[12] = {};
  col[s] = 1; consumed[s] = true;
  int row = 1;
  for (int b = 0; b < 12 && row < 4; ++b)
    if (lo[b] && ln[b] && !consumed[b]) { col[b] = 1 << row; uo[b]=un[b]=true; consumed[b]=true; ++row; }
  while (row < 4) {
    int a = -1, c = -1;
    for (int b = 0; b < 12; ++b) if (lo[b] && !uo[b] && !consumed[b]) { a = b; break; }
    for (int b = 0; b < 12; ++b) if (ln[b] && !un[b] && !consumed[b] && b != a) { c = b; break; }
    if (a < 0 || c < 0) { R.ok = false; return R; }
    col[a] |= 1 << row; col[c] |= 1 << row;
    uo[a]=true; un[c]=true; consumed[c]=true;     // a still needs an identity row
    ++row;
  }
  if (local) {
    for (int i = 0; i < 3; ++i) {
      if (consumed[o.wav[i]]) { R.ok = false; return R; }
      col[o.wav[i]] |= 1 << (9 + i);
      consumed[o.wav[i]] = true;
    }
    int rr = 4;
    for (int b = 0; b < 12; ++b) if (!consumed[b]) { col[b] |= 1 << rr; ++rr; }
    if (rr != 9) { R.ok = false; return R; }
  } else {
    int rr = 4;
    for (int b = 0; b < 12; ++b) if (!consumed[b]) { col[b] |= 1 << rr; ++rr; }
    if (rr != 12) { R.ok = false; return R; }
  }
  {                                     // rank-12 invertibility over GF(2)
    int pv[12] = {}, pb[12] = {};
    int nr = 0;
    for (int b = 0; b < 12; ++b) {
      int v = col[b];
      for (int k = 0; k < nr; ++k) if (v & pb[k]) v ^= pv[k];
      if (v) { pb[nr] = v & (-v); pv[nr] = v; ++nr; }
    }
    if (nr != 12) { R.ok = false; return R; }
  }
  int Lo[6] = {}, Ln[6] = {};
  int i0 = 0, i1 = 0;
  for (int b = 0; b < 12; ++b) { if (lo[b]) Lo[i0++] = b; if (ln[b]) Ln[i1++] = b; }
  if (i0 != 6 || i1 != 6) { R.ok = false; return R; }
  for (int i = 0; i < 9; ++i) {
    unsigned po = (i < 6) ? (unsigned)col[Lo[i]] : (unsigned)col[o.wav[i-6]];
    unsigned pn = (i < 6) ? (unsigned)col[Ln[i]] : (unsigned)col[n.wav[i-6]];
    R.m.pk[i] = po | (pn << 16);
  }
  for (int r = 0; r < 8; ++r) {
    int a = 0, c = 0;
    for (int j = 0; j < 3; ++j)
      if ((r >> j) & 1) { a ^= col[o.reg[j]]; c ^= col[n.reg[j]]; }
    R.m.so[r] = (unsigned short)(a * 8);
    R.m.rn[r] = (unsigned short)(c * 8);
  }
  return R;
}

struct AllT { TMap t[37]; bool loc[37]; int js[37]; int jn[37]; bool ok; };
constexpr AllT buildAll() {
  AllT A = {};
  A.ok = true;
  for (int t = 0; t < 37; ++t) {
    BuildOut b = buildT(phaseAt(t), phaseAt(t + 1), isLoc(t));
    A.t[t] = b.m;
    A.ok = A.ok && b.ok;
    A.loc[t] = isLoc(t);
    A.js[t] = b.js;
    A.jn[t] = b.jn;
  }
  return A;
}
constexpr AllT AT = buildAll();
static_assert(AT.ok, "slot-map construction failed");

// ---------------- angle fetch via v_readlane --------------------------------
__device__ __forceinline__ float rlf(float v, int l) {
  return __int_as_float(__builtin_amdgcn_readlane(__float_as_int(v), l));
}
template<int AO>
__device__ __forceinline__ v2f angAt(const float (&ct)[3], const float (&st)[3]) {
  v2f a;
  a.x = rlf(ct[AO >> 6], AO & 63);
  a.y = rlf(st[AO >> 6], AO & 63);
  return a;
}

// ---------------- gates on the 8-amplitude register file --------------------
template<int J>
__device__ __forceinline__ void ry8(v2f (&z)[8], v2f a) {
  const float c = a.x, s = a.y;
  #pragma unroll
  for (int p = 0; p < 4; ++p) {
    const int r0 = ((p & ~((1 << J) - 1)) << 1) | (p & ((1 << J) - 1));
    const int r1 = r0 | (1 << J);
    v2f u = z[r0], v = z[r1];
    z[r0] = c * u - s * v;
    z[r1] = s * u + c * v;
  }
}
// CRX, off-diagonal -i*s (validated R1-R10)
template<int JC, int JT>
__device__ __forceinline__ void crx8(v2f (&z)[8], v2f a) {
  const float c = a.x, s = a.y;
  constexpr int MC = 1 << JC, MT = 1 << JT;
  constexpr int mlo = MC < MT ? MC : MT;
  constexpr int mhi = MC < MT ? MT : MC;
  #pragma unroll
  for (int p = 0; p < 2; ++p) {
    int q = ((p & ~(mlo - 1)) << 1) | (p & (mlo - 1));
    q = ((q & ~(mhi - 1)) << 1) | (q & (mhi - 1));
    const int r0 = q | MC, r1 = r0 | MT;
    v2f u = z[r0], v = z[r1];
    v2f n0, n1;
    n0.x = c * u.x + s * v.y;
    n0.y = c * u.y - s * v.x;
    n1.x = c * v.x + s * u.y;
    n1.y = c * v.y - s * u.x;
    z[r0] = n0; z[r1] = n1;
  }
}

// Epoch gate lists — verbatim from the R6-R10-validated schedule.
template<int E, int L>
__device__ __forceinline__ void gates(v2f (&z)[8], const float (&ct)[3], const float (&st)[3]) {
#define A(k) (angAt<48 * L + (k)>(ct, st))
  if constexpr (E == 0)      { ry8<0>(z,A(0));  ry8<1>(z,A(11)); ry8<2>(z,A(10));
                               crx8<1,0>(z,A(12)); crx8<2,1>(z,A(13)); }
  else if constexpr (E == 1) { ry8<1>(z,A(9));  ry8<2>(z,A(8));
                               crx8<1,0>(z,A(14)); crx8<2,1>(z,A(15)); }
  else if constexpr (E == 2) { ry8<1>(z,A(7));  ry8<2>(z,A(6));
                               crx8<1,0>(z,A(16)); crx8<2,1>(z,A(17)); }
  else if constexpr (E == 3) { ry8<1>(z,A(5));  ry8<2>(z,A(4));
                               crx8<1,0>(z,A(18)); crx8<2,1>(z,A(19)); }
  else if constexpr (E == 4) { ry8<1>(z,A(3));  ry8<2>(z,A(2));
                               crx8<1,0>(z,A(20)); crx8<2,1>(z,A(21)); }
  else if constexpr (E == 5) { ry8<1>(z,A(1));
                               crx8<1,0>(z,A(22)); crx8<2,1>(z,A(23)); }
  else if constexpr (E == 6) { ry8<0>(z,A(24)); ry8<1>(z,A(35)); ry8<2>(z,A(34));
                               crx8<1,2>(z,A(36)); crx8<0,1>(z,A(37)); }
  else if constexpr (E == 7) { ry8<0>(z,A(26)); ry8<1>(z,A(25));
                               crx8<1,2>(z,A(38)); crx8<0,1>(z,A(39)); }
  else if constexpr (E == 8) { ry8<0>(z,A(28)); ry8<1>(z,A(27));
                               crx8<1,2>(z,A(40)); crx8<0,1>(z,A(41)); }
  else if constexpr (E == 9) { ry8<0>(z,A(30)); ry8<1>(z,A(29));
                               crx8<1,2>(z,A(42)); crx8<0,1>(z,A(43)); }
  else if constexpr (E == 10){ ry8<0>(z,A(32)); ry8<1>(z,A(31));
                               crx8<1,2>(z,A(44)); crx8<0,1>(z,A(45)); }
  else                       { ry8<1>(z,A(33));
                               crx8<1,2>(z,A(46)); crx8<0,1>(z,A(47)); }
#undef A
}

// Restage for this element. Local: private-wave region of Lb, in-order LDS,
// no sync. Cross: single C buffer, barrier-stash-barrier-unstash (leading
// barrier covers the WAR vs the previous cross's laggard readers; every wave
// passed that cross's trailing barrier after its reads).
template<int T>
__device__ __forceinline__ void restage(v2f (&z)[8], int t9, char* Lb, char* C) {
  constexpr bool LOC = AT.loc[T];
  constexpr int JS = AT.js[T], JN = AT.jn[T];
  char* buf = LOC ? Lb : C;
  unsigned acc = 0;
  #pragma unroll
  for (int i = 0; i < 9; ++i)
    acc ^= (unsigned)(-((t9 >> i) & 1)) & AT.t[T].pk[i];
  const unsigned bo = (acc & 0xfffu) << 3;
  const unsigned bn = ((acc >> 16) & 0xfffu) << 3;
  if constexpr (!LOC) __syncthreads();
  // stash: 4 x ds_write_b128, pairing regs over the shared bit (slot bit 0)
  #pragma unroll
  for (int r = 0; r < 8; ++r) {
    if (r & (1 << JS)) continue;
    v2f z0 = z[r], z1 = z[r | (1 << JS)];
    float4 w; w.x = z0.x; w.y = z0.y; w.z = z1.x; w.w = z1.y;
    *(float4*)(buf + (bo ^ AT.t[T].so[r])) = w;
  }
  if constexpr (LOC) {
    // same-wave LDS ops are serviced in program order (R7-validated):
    // reads queue behind writes — only a compiler fence needed.
    asm volatile("" ::: "memory");
  } else {
    __syncthreads();
  }
  // unstash: 4 x ds_read_b128
  #pragma unroll
  for (int r = 0; r < 8; ++r) {
    if (r & (1 << JN)) continue;
    float4 w = *(const float4*)(buf + (bn ^ AT.t[T].rn[r]));
    v2f z0, z1;
    z0.x = w.x; z0.y = w.y;
    z1.x = w.z; z1.y = w.w;
    z[r] = z0;
    z[r | (1 << JN)] = z1;
  }
}

template<int L>
__device__ __forceinline__ void layer(v2f (&z)[8], int t9,
                                      const float (&ct)[3], const float (&st)[3],
                                      char* Lb, char* C) {
  gates<0, L>(z, ct, st);  restage<12*L + 1>(z, t9, Lb, C);
  gates<1, L>(z, ct, st);  restage<12*L + 2>(z, t9, Lb, C);
  gates<2, L>(z, ct, st);  restage<12*L + 3>(z, t9, Lb, C);
  gates<3, L>(z, ct, st);  restage<12*L + 4>(z, t9, Lb, C);
  gates<4, L>(z, ct, st);  restage<12*L + 5>(z, t9, Lb, C);
  gates<5, L>(z, ct, st);  restage<12*L + 6>(z, t9, Lb, C);
  gates<6, L>(z, ct, st);  restage<12*L + 7>(z, t9, Lb, C);
  gates<7, L>(z, ct, st);  restage<12*L + 8>(z, t9, Lb, C);
  gates<8, L>(z, ct, st);  restage<12*L + 9>(z, t9, Lb, C);
  gates<9, L>(z, ct, st);  restage<12*L + 10>(z, t9, Lb, C);
  gates<10, L>(z, ct, st); restage<12*L + 11>(z, t9, Lb, C);
  gates<11, L>(z, ct, st);
  if constexpr (L < 2) restage<12*L + 12>(z, t9, Lb, C);
}

__global__ __launch_bounds__(BLK, 4) void ansatz_kernel(
    const float* __restrict__ sre, const float* __restrict__ sim,
    const float* __restrict__ params, float* __restrict__ out) {

  __shared__ alignas(16) v2f Lb2[2][DIM];   // per-element local buffer, 64 KB
  __shared__ alignas(16) v2f Cb2[2][DIM];   // per-element cross buffer, 64 KB

  const int tid = threadIdx.x;
  const int el  = tid >> 9;                 // element within block
  const int t9  = tid & 511;                // per-element thread id
  const int b2  = (blockIdx.x << 1) | el;   // global element index
  char* Lb = (char*)Lb2[el];
  char* C  = (char*)Cb2[el];

  // ---- per-wave angle table in lane-distributed VGPRs (no LDS, no barrier)
  float ct[3], st[3];
  {
    const int lane = tid & 63;
    #pragma unroll
    for (int j = 0; j < 3; ++j) {
      int idx = lane + 64 * j;
      int ci = (idx < NPAR) ? idx : 0;
      float th = params[(size_t)b2 * NPAR + ci];
      sincosf(0.5f * th, &st[j], &ct[j]);
    }
  }

  // ---- init: direct gather in epoch-0 layout ----
  // epoch 0: reg {11,0,1} (r0<->bit11, r1<->bit0, r2<->bit1);
  // lanes t9 0..5 -> bits {2,3,4,5,9,10}; waves t9 6..8 -> bits {6,7,8}
  v2f z[8];
  {
    int base = ((t9 & 15) << 2) | ((t9 & 16) << 5) | ((t9 & 32) << 5)
             | (t9 & 64) | (t9 & 128) | (t9 & 256);
    const float4* pr = (const float4*)(sre + (size_t)b2 * DIM + base);
    const float4* pi = (const float4*)(sim + (size_t)b2 * DIM + base);
    float4 f0 = pr[0], f1 = pr[512];      // +2048 amps (bit 11)
    float4 g0 = pi[0], g1 = pi[512];
    z[0].x = f0.x; z[0].y = g0.x;  z[2].x = f0.y; z[2].y = g0.y;
    z[4].x = f0.z; z[4].y = g0.z;  z[6].x = f0.w; z[6].y = g0.w;
    z[1].x = f1.x; z[1].y = g1.x;  z[3].x = f1.y; z[3].y = g1.y;
    z[5].x = f1.z; z[5].y = g1.z;  z[7].x = f1.w; z[7].y = g1.w;
  }

  layer<0>(z, t9, ct, st, Lb, C);
  layer<1>(z, t9, ct, st, Lb, C);
  layer<2>(z, t9, ct, st, Lb, C);

  // ---- final: direct scatter store from epoch-11 layout ----
  // epoch 11: reg {1,2,3} (amp = base + 2*r); lanes t9 0..5 -> bits
  // {0,4,5,9,10,11}; waves t9 6..8 -> bits {6,7,8}
  {
    int base = (t9 & 1) | ((t9 & 2) << 3) | ((t9 & 4) << 3)
             | ((t9 & 8) << 6) | ((t9 & 16) << 6) | ((t9 & 32) << 6)
             | (t9 & 64) | (t9 & 128) | (t9 & 256);
    v2f* o2 = (v2f*)out + (size_t)b2 * DIM + base;
    #pragma unroll
    for (int r = 0; r < 8; ++r)
      o2[2 * r] = z[r];
  }
}

extern "C" void kernel_launch(void* const* d_in, const int* in_sizes, int n_in,
                              void* d_out, int out_size, void* d_ws, size_t ws_size,
                              hipStream_t stream) {
  const float* sre    = (const float*)d_in[0];
  const float* sim    = (const float*)d_in[1];
  const float* params = (const float*)d_in[2];
  float* out          = (float*)d_out;

  const int B = in_sizes[0] / DIM;   // 128
  ansatz_kernel<<<B / 2, BLK, 0, stream>>>(sre, sim, params, out);
}

// Round 12
// 78.881 us; speedup vs baseline: 1.1714x; 1.1714x over previous
//
#include <hip/hip_runtime.h>
#include <math.h>

#define DIM  4096
#define BLK  512            // 8 waves; 8 amplitudes (v2f) per thread; 2 waves/SIMD
#define NPAR 144

typedef float v2f __attribute__((ext_vector_type(2)));

// ---------------------------------------------------------------------------
// R12 = revert to R9 (best measured: dur 78.9, kernel ~28 us).
// 12 canonical state bits per phase: 3 register bits, 3 wave bits (tid 6..8),
// 6 lane bits (tid 0..5). Gates act on register-local bits. 12 epochs/layer.
// Wave-pinned runs -> wave-local restages (no barrier, no waitcnt: LDS is
// in-order per wave). Transition windows share one reg bit -> full b128
// stash AND unstash. Angles in lane-distributed VGPRs via v_readlane.
// ---------------------------------------------------------------------------
struct Ph { int reg[3]; int wav[3]; };
struct TMap { unsigned pk[9]; unsigned short so[8]; unsigned short rn[8]; };

constexpr int REGS[12][3] = {
  {11,0,1},{1,2,3},{3,4,5},{5,6,7},{7,8,9},{9,10,11},
  {11,0,1},{9,10,11},{7,8,9},{5,6,7},{3,4,5},{1,2,3}};

constexpr Ph phaseAt(int i) {         // i = 0..37; 0/37 = global pseudo-phase
  Ph p = {};
  if (i == 0 || i == 37) {
    p.reg[0]=0; p.reg[1]=1; p.reg[2]=2;
    p.wav[0]=9; p.wav[1]=10; p.wav[2]=11;
    return p;
  }
  int e = (i - 1) % 12;
  for (int j = 0; j < 3; ++j) p.reg[j] = REGS[e][j];
  bool A = (e <= 2) || (e >= 10);     // pin {6,7,8} else {2,3,4}
  p.wav[0] = A ? 6 : 2; p.wav[1] = A ? 7 : 3; p.wav[2] = A ? 8 : 4;
  return p;
}
constexpr bool inArr(const int* a, int n, int b) {
  for (int i = 0; i < n; ++i) if (a[i] == b) return true;
  return false;
}
constexpr int idxOf3(const int* a, int v) {
  for (int j = 0; j < 3; ++j) if (a[j] == v) return j;
  return -1;
}
constexpr bool isLoc(int t) {
  if (t == 0 || t == 36) return false;
  Ph a = phaseAt(t), b = phaseAt(t + 1);
  return a.wav[0]==b.wav[0] && a.wav[1]==b.wav[1] && a.wav[2]==b.wav[2];
}
constexpr int bufIdx(int t) {
  int k = 0;
  for (int u = 0; u <= t; ++u) if (!isLoc(u)) ++k;
  return (k + 1) & 1;
}
constexpr int sharedBit(Ph o, Ph n) {
  for (int j = 0; j < 3; ++j) if (inArr(n.reg, 3, o.reg[j])) return o.reg[j];
  return -1;
}

struct BuildOut { TMap m; int js, jn; bool ok; };

// GF(2)-linear canonical->slot map (R7-validated). Row 0 = shared reg bit
// (b128 pairing both sides). Rows 1..3 = lane bits of both phases (bank-
// conflict-free b128). Local: wave bits -> rows 9..11 (private 4 KB/wave).
constexpr BuildOut buildT(Ph o, Ph n, bool local) {
  BuildOut R = {};
  R.ok = true;
  int s = sharedBit(o, n);
  if (s < 0) { R.ok = false; return R; }
  R.js = idxOf3(o.reg, s);
  R.jn = idxOf3(n.reg, s);
  if (R.js < 0 || R.jn < 0) { R.ok = false; return R; }
  bool lo[12] = {}, ln[12] = {};
  for (int b = 0; b < 12; ++b) {
    lo[b] = !inArr(o.reg,3,b) && !inArr(o.wav,3,b);
    ln[b] = !inArr(n.reg,3,b) && !inArr(n.wav,3,b);
  }
  int col[12] = {};
  bool uo[12] = {}, un[12] = {}, consumed[12] = {};
  col[s] = 1; consumed[s] = true;
  int row = 1;
  for (int b = 0; b < 12 && row < 4; ++b)
    if (lo[b] && ln[b] && !consumed[b]) { col[b] = 1 << row; uo[b]=un[b]=true; consumed[b]=true; ++row; }
  while (row < 4) {
    int a = -1, c = -1;
    for (int b = 0; b < 12; ++b) if (lo[b] && !uo[b] && !consumed[b]) { a = b; break; }
    for (int b = 0; b < 12; ++b) if (ln[b] && !un[b] && !consumed[b] && b != a) { c = b; break; }
    if (a < 0 || c < 0) { R.ok = false; return R; }
    col[a] |= 1 << row; col[c] |= 1 << row;
    uo[a]=true; un[c]=true; consumed[c]=true;     // a still needs an identity row
    ++row;
  }
  if (local) {
    for (int i = 0; i < 3; ++i) {
      if (consumed[o.wav[i]]) { R.ok = false; return R; }
      col[o.wav[i]] |= 1 << (9 + i);
      consumed[o.wav[i]] = true;
    }
    int rr = 4;
    for (int b = 0; b < 12; ++b) if (!consumed[b]) { col[b] |= 1 << rr; ++rr; }
    if (rr != 9) { R.ok = false; return R; }
  } else {
    int rr = 4;
    for (int b = 0; b < 12; ++b) if (!consumed[b]) { col[b] |= 1 << rr; ++rr; }
    if (rr != 12) { R.ok = false; return R; }
  }
  {                                     // rank-12 invertibility over GF(2)
    int pv[12] = {}, pb[12] = {};
    int nr = 0;
    for (int b = 0; b < 12; ++b) {
      int v = col[b];
      for (int k = 0; k < nr; ++k) if (v & pb[k]) v ^= pv[k];
      if (v) { pb[nr] = v & (-v); pv[nr] = v; ++nr; }
    }
    if (nr != 12) { R.ok = false; return R; }
  }
  int Lo[6] = {}, Ln[6] = {};
  int i0 = 0, i1 = 0;
  for (int b = 0; b < 12; ++b) { if (lo[b]) Lo[i0++] = b; if (ln[b]) Ln[i1++] = b; }
  if (i0 != 6 || i1 != 6) { R.ok = false; return R; }
  for (int i = 0; i < 9; ++i) {
    unsigned po = (i < 6) ? (unsigned)col[Lo[i]] : (unsigned)col[o.wav[i-6]];
    unsigned pn = (i < 6) ? (unsigned)col[Ln[i]] : (unsigned)col[n.wav[i-6]];
    R.m.pk[i] = po | (pn << 16);
  }
  for (int r = 0; r < 8; ++r) {
    int a = 0, c = 0;
    for (int j = 0; j < 3; ++j)
      if ((r >> j) & 1) { a ^= col[o.reg[j]]; c ^= col[n.reg[j]]; }
    R.m.so[r] = (unsigned short)(a * 8);
    R.m.rn[r] = (unsigned short)(c * 8);
  }
  return R;
}

struct AllT { TMap t[37]; bool loc[37]; int buf[37]; int js[37]; int jn[37]; bool ok; };
constexpr AllT buildAll() {
  AllT A = {};
  A.ok = true;
  for (int t = 0; t < 37; ++t) {
    BuildOut b = buildT(phaseAt(t), phaseAt(t + 1), isLoc(t));
    A.t[t] = b.m;
    A.ok = A.ok && b.ok;
    A.loc[t] = isLoc(t);
    A.buf[t] = bufIdx(t);
    A.js[t] = b.js;
    A.jn[t] = b.jn;
  }
  return A;
}
constexpr AllT AT = buildAll();
static_assert(AT.ok, "slot-map construction failed");

// ---------------- angle fetch via v_readlane --------------------------------
__device__ __forceinline__ float rlf(float v, int l) {
  return __int_as_float(__builtin_amdgcn_readlane(__float_as_int(v), l));
}
template<int AO>
__device__ __forceinline__ v2f angAt(const float (&ct)[3], const float (&st)[3]) {
  v2f a;
  a.x = rlf(ct[AO >> 6], AO & 63);
  a.y = rlf(st[AO >> 6], AO & 63);
  return a;
}

// ---------------- gates on the 8-amplitude register file --------------------
template<int J>
__device__ __forceinline__ void ry8(v2f (&z)[8], v2f a) {
  const float c = a.x, s = a.y;
  #pragma unroll
  for (int p = 0; p < 4; ++p) {
    const int r0 = ((p & ~((1 << J) - 1)) << 1) | (p & ((1 << J) - 1));
    const int r1 = r0 | (1 << J);
    v2f u = z[r0], v = z[r1];
    z[r0] = c * u - s * v;
    z[r1] = s * u + c * v;
  }
}
// CRX, off-diagonal -i*s (validated R1-R11)
template<int JC, int JT>
__device__ __forceinline__ void crx8(v2f (&z)[8], v2f a) {
  const float c = a.x, s = a.y;
  constexpr int MC = 1 << JC, MT = 1 << JT;
  constexpr int mlo = MC < MT ? MC : MT;
  constexpr int mhi = MC < MT ? MT : MC;
  #pragma unroll
  for (int p = 0; p < 2; ++p) {
    int q = ((p & ~(mlo - 1)) << 1) | (p & (mlo - 1));
    q = ((q & ~(mhi - 1)) << 1) | (q & (mhi - 1));
    const int r0 = q | MC, r1 = r0 | MT;
    v2f u = z[r0], v = z[r1];
    v2f n0, n1;
    n0.x = c * u.x + s * v.y;
    n0.y = c * u.y - s * v.x;
    n1.x = c * v.x + s * u.y;
    n1.y = c * v.y - s * u.x;
    z[r0] = n0; z[r1] = n1;
  }
}

// Epoch gate lists — verbatim from the R6-R11-validated schedule.
template<int E, int L>
__device__ __forceinline__ void gates(v2f (&z)[8], const float (&ct)[3], const float (&st)[3]) {
#define A(k) (angAt<48 * L + (k)>(ct, st))
  if constexpr (E == 0)      { ry8<0>(z,A(0));  ry8<1>(z,A(11)); ry8<2>(z,A(10));
                               crx8<1,0>(z,A(12)); crx8<2,1>(z,A(13)); }
  else if constexpr (E == 1) { ry8<1>(z,A(9));  ry8<2>(z,A(8));
                               crx8<1,0>(z,A(14)); crx8<2,1>(z,A(15)); }
  else if constexpr (E == 2) { ry8<1>(z,A(7));  ry8<2>(z,A(6));
                               crx8<1,0>(z,A(16)); crx8<2,1>(z,A(17)); }
  else if constexpr (E == 3) { ry8<1>(z,A(5));  ry8<2>(z,A(4));
                               crx8<1,0>(z,A(18)); crx8<2,1>(z,A(19)); }
  else if constexpr (E == 4) { ry8<1>(z,A(3));  ry8<2>(z,A(2));
                               crx8<1,0>(z,A(20)); crx8<2,1>(z,A(21)); }
  else if constexpr (E == 5) { ry8<1>(z,A(1));
                               crx8<1,0>(z,A(22)); crx8<2,1>(z,A(23)); }
  else if constexpr (E == 6) { ry8<0>(z,A(24)); ry8<1>(z,A(35)); ry8<2>(z,A(34));
                               crx8<1,2>(z,A(36)); crx8<0,1>(z,A(37)); }
  else if constexpr (E == 7) { ry8<0>(z,A(26)); ry8<1>(z,A(25));
                               crx8<1,2>(z,A(38)); crx8<0,1>(z,A(39)); }
  else if constexpr (E == 8) { ry8<0>(z,A(28)); ry8<1>(z,A(27));
                               crx8<1,2>(z,A(40)); crx8<0,1>(z,A(41)); }
  else if constexpr (E == 9) { ry8<0>(z,A(30)); ry8<1>(z,A(29));
                               crx8<1,2>(z,A(42)); crx8<0,1>(z,A(43)); }
  else if constexpr (E == 10){ ry8<0>(z,A(32)); ry8<1>(z,A(31));
                               crx8<1,2>(z,A(44)); crx8<0,1>(z,A(45)); }
  else                       { ry8<1>(z,A(33));
                               crx8<1,2>(z,A(46)); crx8<0,1>(z,A(47)); }
#undef A
}

template<int T>
__device__ __forceinline__ void restage(v2f (&z)[8], int tid, char* Lb, char* C0, char* C1) {
  constexpr bool LOC = AT.loc[T];
  constexpr int JS = AT.js[T], JN = AT.jn[T];
  char* buf = LOC ? Lb : (AT.buf[T] ? C1 : C0);
  unsigned acc = 0;
  #pragma unroll
  for (int i = 0; i < 9; ++i)
    acc ^= (unsigned)(-((tid >> i) & 1)) & AT.t[T].pk[i];
  const unsigned bo = (acc & 0xfffu) << 3;
  const unsigned bn = ((acc >> 16) & 0xfffu) << 3;
  // stash: 4 x ds_write_b128, pairing regs over the shared bit (slot bit 0)
  #pragma unroll
  for (int r = 0; r < 8; ++r) {
    if (r & (1 << JS)) continue;
    v2f z0 = z[r], z1 = z[r | (1 << JS)];
    float4 w; w.x = z0.x; w.y = z0.y; w.z = z1.x; w.w = z1.y;
    *(float4*)(buf + (bo ^ AT.t[T].so[r])) = w;
  }
  if (LOC) {
    // same-wave LDS ops are serviced in program order (R7-validated):
    // reads queue behind writes — only a compiler fence needed.
    asm volatile("" ::: "memory");
  } else {
    __syncthreads();
  }
  // unstash: 4 x ds_read_b128
  #pragma unroll
  for (int r = 0; r < 8; ++r) {
    if (r & (1 << JN)) continue;
    float4 w = *(const float4*)(buf + (bn ^ AT.t[T].rn[r]));
    v2f z0, z1;
    z0.x = w.x; z0.y = w.y;
    z1.x = w.z; z1.y = w.w;
    z[r] = z0;
    z[r | (1 << JN)] = z1;
  }
}

template<int L>
__device__ __forceinline__ void layer(v2f (&z)[8], int tid,
                                      const float (&ct)[3], const float (&st)[3],
                                      char* Lb, char* C0, char* C1) {
  gates<0, L>(z, ct, st);  restage<12*L + 1>(z, tid, Lb, C0, C1);
  gates<1, L>(z, ct, st);  restage<12*L + 2>(z, tid, Lb, C0, C1);
  gates<2, L>(z, ct, st);  restage<12*L + 3>(z, tid, Lb, C0, C1);
  gates<3, L>(z, ct, st);  restage<12*L + 4>(z, tid, Lb, C0, C1);
  gates<4, L>(z, ct, st);  restage<12*L + 5>(z, tid, Lb, C0, C1);
  gates<5, L>(z, ct, st);  restage<12*L + 6>(z, tid, Lb, C0, C1);
  gates<6, L>(z, ct, st);  restage<12*L + 7>(z, tid, Lb, C0, C1);
  gates<7, L>(z, ct, st);  restage<12*L + 8>(z, tid, Lb, C0, C1);
  gates<8, L>(z, ct, st);  restage<12*L + 9>(z, tid, Lb, C0, C1);
  gates<9, L>(z, ct, st);  restage<12*L + 10>(z, tid, Lb, C0, C1);
  gates<10, L>(z, ct, st); restage<12*L + 11>(z, tid, Lb, C0, C1);
  gates<11, L>(z, ct, st);
  if constexpr (L < 2) restage<12*L + 12>(z, tid, Lb, C0, C1);
}

__global__ __launch_bounds__(BLK) void ansatz_kernel(
    const float* __restrict__ sre, const float* __restrict__ sim,
    const float* __restrict__ params, float* __restrict__ out) {

  __shared__ alignas(16) v2f C0s[DIM], C1s[DIM], Ls[DIM];   // 3 x 32 KB

  const int b = blockIdx.x, tid = threadIdx.x;
  char* C0 = (char*)C0s;
  char* C1 = (char*)C1s;
  char* Lb = (char*)Ls;

  // ---- per-wave angle table in lane-distributed VGPRs (no LDS, no barrier)
  float ct[3], st[3];
  {
    const int lane = tid & 63;
    #pragma unroll
    for (int j = 0; j < 3; ++j) {
      int idx = lane + 64 * j;
      int ci = (idx < NPAR) ? idx : 0;
      float th = params[(size_t)b * NPAR + ci];
      sincosf(0.5f * th, &st[j], &ct[j]);
    }
  }

  // ---- init: direct gather in epoch-0 layout ----
  // epoch 0: reg {11,0,1} (r0<->bit11, r1<->bit0, r2<->bit1);
  // lanes tid0..5 -> bits {2,3,4,5,9,10}; waves tid6..8 -> bits {6,7,8}
  v2f z[8];
  {
    int base = ((tid & 15) << 2) | ((tid & 16) << 5) | ((tid & 32) << 5)
             | (tid & 64) | (tid & 128) | (tid & 256);
    const float4* pr = (const float4*)(sre + (size_t)b * DIM + base);
    const float4* pi = (const float4*)(sim + (size_t)b * DIM + base);
    float4 f0 = pr[0], f1 = pr[512];      // +2048 amps (bit 11)
    float4 g0 = pi[0], g1 = pi[512];
    z[0].x = f0.x; z[0].y = g0.x;  z[2].x = f0.y; z[2].y = g0.y;
    z[4].x = f0.z; z[4].y = g0.z;  z[6].x = f0.w; z[6].y = g0.w;
    z[1].x = f1.x; z[1].y = g1.x;  z[3].x = f1.y; z[3].y = g1.y;
    z[5].x = f1.z; z[5].y = g1.z;  z[7].x = f1.w; z[7].y = g1.w;
  }

  layer<0>(z, tid, ct, st, Lb, C0, C1);
  layer<1>(z, tid, ct, st, Lb, C0, C1);
  layer<2>(z, tid, ct, st, Lb, C0, C1);

  // ---- final: direct scatter store from epoch-11 layout ----
  // epoch 11: reg {1,2,3} (amp = base + 2*r); lanes tid0..5 -> bits
  // {0,4,5,9,10,11}; waves tid6..8 -> bits {6,7,8}
  {
    int base = (tid & 1) | ((tid & 2) << 3) | ((tid & 4) << 3)
             | ((tid & 8) << 6) | ((tid & 16) << 6) | ((tid & 32) << 6)
             | (tid & 64) | (tid & 128) | (tid & 256);
    v2f* o2 = (v2f*)out + (size_t)b * DIM + base;
    #pragma unroll
    for (int r = 0; r < 8; ++r)
      o2[2 * r] = z[r];
  }
}

extern "C" void kernel_launch(void* const* d_in, const int* in_sizes, int n_in,
                              void* d_out, int out_size, void* d_ws, size_t ws_size,
                              hipStream_t stream) {
  const float* sre    = (const float*)d_in[0];
  const float* sim    = (const float*)d_in[1];
  const float* params = (const float*)d_in[2];
  float* out          = (float*)d_out;

  const int B = in_sizes[0] / DIM;   // 128
  ansatz_kernel<<<B, BLK, 0, stream>>>(sre, sim, params, out);
}